// Round 1
// baseline (961.224 us; speedup 1.0000x reference)
//
#include <hip/hip_runtime.h>
#include <hip/hip_bf16.h>

using bf16 = __hip_bfloat16;
typedef __attribute__((ext_vector_type(4))) float f32x4;
typedef __attribute__((ext_vector_type(8))) __bf16 bf16x8;

static constexpr int Tn = 8192;           // tokens = B*S = 4*2048
static constexpr int D  = 4096;           // in features (K)
static constexpr int QO = 4096, KO = 1024, VO = 1024;
static constexpr int NO = QO + KO + VO;   // 6144 fused out features

// ---------------- cast x fp32 -> bf16 (8 elems/thread) ----------------
__global__ void cast_x_kernel(const float* __restrict__ x, bf16* __restrict__ xb) {
    size_t i = ((size_t)blockIdx.x * blockDim.x + threadIdx.x) * 8;
    float4 a = *(const float4*)(x + i);
    float4 b = *(const float4*)(x + i + 4);
    union { bf16 h[8]; uint4 u; } pk;
    pk.h[0] = __float2bfloat16(a.x); pk.h[1] = __float2bfloat16(a.y);
    pk.h[2] = __float2bfloat16(a.z); pk.h[3] = __float2bfloat16(a.w);
    pk.h[4] = __float2bfloat16(b.x); pk.h[5] = __float2bfloat16(b.y);
    pk.h[6] = __float2bfloat16(b.z); pk.h[7] = __float2bfloat16(b.w);
    *(uint4*)(xb + i) = pk.u;
}

// ------------- dequant q/k/v codes -> fused bf16 W [NO][D] -------------
__global__ void dequant_kernel(
    const int* __restrict__ qc, const float* __restrict__ qs, const float* __restrict__ qcb,
    const int* __restrict__ kc, const float* __restrict__ ks, const float* __restrict__ kcb,
    const int* __restrict__ vc, const float* __restrict__ vs, const float* __restrict__ vcb,
    bf16* __restrict__ W) {
    __shared__ float cb[48];
    int t = threadIdx.x;
    if (t < 48) cb[t] = (t < 16) ? qcb[t] : (t < 32 ? kcb[t - 16] : vcb[t - 32]);
    __syncthreads();
    size_t idx = ((size_t)blockIdx.x * 256 + t) * 8;   // elem index into W
    int o = (int)(idx >> 12);        // D == 4096 == 2^12
    int c = (int)(idx & 4095);
    const int* codes; const float* scales; int cbo; int ro;
    if (o < QO)           { codes = qc; scales = qs; cbo = 0;  ro = o; }
    else if (o < QO + KO) { codes = kc; scales = ks; cbo = 16; ro = o - QO; }
    else                  { codes = vc; scales = vs; cbo = 32; ro = o - QO - KO; }
    float s = scales[ro * (D / 128) + (c >> 7)];       // GROUP = 128
    const int4* cp = (const int4*)(codes + (size_t)ro * D + c);
    int4 c0 = cp[0], c1 = cp[1];
    union { bf16 h[8]; uint4 u; } pk;
    pk.h[0] = __float2bfloat16(cb[cbo + c0.x] * s);
    pk.h[1] = __float2bfloat16(cb[cbo + c0.y] * s);
    pk.h[2] = __float2bfloat16(cb[cbo + c0.z] * s);
    pk.h[3] = __float2bfloat16(cb[cbo + c0.w] * s);
    pk.h[4] = __float2bfloat16(cb[cbo + c1.x] * s);
    pk.h[5] = __float2bfloat16(cb[cbo + c1.y] * s);
    pk.h[6] = __float2bfloat16(cb[cbo + c1.z] * s);
    pk.h[7] = __float2bfloat16(cb[cbo + c1.w] * s);
    *(uint4*)(W + idx) = pk.u;
}

// ---------------- bf16 MFMA GEMM: C[T,NO] = X[T,D] * W[NO,D]^T ----------------
// 128x128 tile, BK=64, 256 threads = 4 waves in 2x2, each wave 64x64 (4x4 MFMA tiles)
#define BM 128
#define BN 128
#define BK 64

#define ASYNC16(g, l)                                              \
    __builtin_amdgcn_global_load_lds(                              \
        (const __attribute__((address_space(1))) void*)(g),        \
        (__attribute__((address_space(3))) void*)(l), 16, 0, 0)

__global__ __launch_bounds__(256) void gemm_qkv_kernel(
    const bf16* __restrict__ A,   // [Tn][D] bf16
    const bf16* __restrict__ Bm,  // [NO][D] bf16
    float* __restrict__ out) {
    __shared__ __align__(16) bf16 lA[BM * BK];  // 16 KB, row stride BK
    __shared__ __align__(16) bf16 lB[BN * BK];  // 16 KB

    const int t    = threadIdx.x;
    const int wave = t >> 6;
    const int lane = t & 63;

    const int m0 = blockIdx.y * BM;
    const int n0 = blockIdx.x * BN;

    const int wm = (wave >> 1) * 64;   // wave row offset in tile
    const int wn = (wave & 1) * 64;    // wave col offset in tile

    f32x4 acc[4][4] = {};

    // staging: per wave-issue, 64 lanes x 16B = 8 rows of BK=64 bf16
    const int srow = lane >> 3;          // 0..7 row within issue
    const int scol = (lane & 7) * 8;     // 0..56 col (8 bf16 = 16B)

    const int quad  = lane >> 4;         // 0..3
    const int l16   = lane & 15;

    for (int kt = 0; kt < D; kt += BK) {
        #pragma unroll
        for (int i = 0; i < 4; ++i) {
            int row = (wave * 4 + i) * 8 + srow;                  // 0..127
            const bf16* gA = A + (size_t)(m0 + row) * D + kt + scol;
            ASYNC16(gA, &lA[(wave * 4 + i) * 8 * BK]);
            const bf16* gB = Bm + (size_t)(n0 + row) * D + kt + scol;
            ASYNC16(gB, &lB[(wave * 4 + i) * 8 * BK]);
        }
        __syncthreads();   // compiler emits vmcnt(0) drain before s_barrier

        #pragma unroll
        for (int s = 0; s < 2; ++s) {
            bf16x8 af[4], bfr[4];
            const int col = s * 32 + quad * 8;
            #pragma unroll
            for (int i = 0; i < 4; ++i)
                af[i] = *(const bf16x8*)&lA[(wm + i * 16 + l16) * BK + col];
            #pragma unroll
            for (int j = 0; j < 4; ++j)
                bfr[j] = *(const bf16x8*)&lB[(wn + j * 16 + l16) * BK + col];
            #pragma unroll
            for (int i = 0; i < 4; ++i)
                #pragma unroll
                for (int j = 0; j < 4; ++j)
                    acc[i][j] = __builtin_amdgcn_mfma_f32_16x16x32_bf16(
                        af[i], bfr[j], acc[i][j], 0, 0, 0);
        }
        __syncthreads();
    }

    // epilogue: map fused column block -> q/k/v output region
    // regions: q [Tn][4096], k [Tn][1024], v [Tn][1024], concatenated flat
    float* base; int ld, c0;
    if (n0 < QO)           { base = out;                               ld = QO; c0 = n0; }
    else if (n0 < QO + KO) { base = out + (size_t)Tn * QO;             ld = KO; c0 = n0 - QO; }
    else                   { base = out + (size_t)Tn * QO + (size_t)Tn * KO; ld = VO; c0 = n0 - QO - KO; }

    const int rquad = quad * 4;   // C/D layout: col = lane&15, row = quad*4 + reg
    #pragma unroll
    for (int i = 0; i < 4; ++i) {
        #pragma unroll
        for (int j = 0; j < 4; ++j) {
            int gc = c0 + wn + j * 16 + l16;
            #pragma unroll
            for (int r = 0; r < 4; ++r) {
                int gr = m0 + wm + i * 16 + rquad + r;
                base[(size_t)gr * ld + gc] = acc[i][j][r];
            }
        }
    }
}

extern "C" void kernel_launch(void* const* d_in, const int* in_sizes, int n_in,
                              void* d_out, int out_size, void* d_ws, size_t ws_size,
                              hipStream_t stream) {
    const float* x   = (const float*)d_in[0];
    const int*   qc  = (const int*)  d_in[1];
    const float* qs  = (const float*)d_in[2];
    const float* qcb = (const float*)d_in[3];
    const int*   kc  = (const int*)  d_in[4];
    const float* ks  = (const float*)d_in[5];
    const float* kcb = (const float*)d_in[6];
    const int*   vc  = (const int*)  d_in[7];
    const float* vs  = (const float*)d_in[8];
    const float* vcb = (const float*)d_in[9];
    float* out = (float*)d_out;

    // workspace: xb = 8192*4096*2 = 64 MB, W = 6144*4096*2 = 48 MB (112 MB total)
    bf16* xb = (bf16*)d_ws;
    bf16* W  = (bf16*)((char*)d_ws + (size_t)Tn * D * sizeof(bf16));

    // 1) cast x -> bf16:  8192*4096/8/256 = 16384 blocks
    cast_x_kernel<<<(Tn * D) / (8 * 256), 256, 0, stream>>>(x, xb);
    // 2) dequant fused W: 6144*4096/8/256 = 12288 blocks
    dequant_kernel<<<((size_t)NO * D) / (8 * 256), 256, 0, stream>>>(
        qc, qs, qcb, kc, ks, kcb, vc, vs, vcb, W);
    // 3) GEMM: grid (NO/128, Tn/128) = (48, 64)
    dim3 grid(NO / BN, Tn / BM);
    gemm_qkv_kernel<<<grid, 256, 0, stream>>>(xb, W, out);
}

// Round 2
// 911.253 us; speedup vs baseline: 1.0548x; 1.0548x over previous
//
#include <hip/hip_runtime.h>
#include <hip/hip_bf16.h>

using bf16 = __hip_bfloat16;
typedef __attribute__((ext_vector_type(4))) float f32x4;
typedef __attribute__((ext_vector_type(8))) __bf16 bf16x8;

static constexpr int Tn = 8192;           // tokens = B*S = 4*2048
static constexpr int D  = 4096;           // in features (K)
static constexpr int QO = 4096, KO = 1024, VO = 1024;
static constexpr int NO = QO + KO + VO;   // 6144 fused out features

// ---------------- cast x fp32 -> bf16 (8 elems/thread) ----------------
__global__ void cast_x_kernel(const float* __restrict__ x, bf16* __restrict__ xb) {
    size_t i = ((size_t)blockIdx.x * blockDim.x + threadIdx.x) * 8;
    float4 a = *(const float4*)(x + i);
    float4 b = *(const float4*)(x + i + 4);
    union { bf16 h[8]; uint4 u; } pk;
    pk.h[0] = __float2bfloat16(a.x); pk.h[1] = __float2bfloat16(a.y);
    pk.h[2] = __float2bfloat16(a.z); pk.h[3] = __float2bfloat16(a.w);
    pk.h[4] = __float2bfloat16(b.x); pk.h[5] = __float2bfloat16(b.y);
    pk.h[6] = __float2bfloat16(b.z); pk.h[7] = __float2bfloat16(b.w);
    *(uint4*)(xb + i) = pk.u;
}

// ------------- dequant q/k/v codes -> fused bf16 W [NO][D] -------------
__global__ void dequant_kernel(
    const int* __restrict__ qc, const float* __restrict__ qs, const float* __restrict__ qcb,
    const int* __restrict__ kc, const float* __restrict__ ks, const float* __restrict__ kcb,
    const int* __restrict__ vc, const float* __restrict__ vs, const float* __restrict__ vcb,
    bf16* __restrict__ W) {
    __shared__ float cb[48];
    int t = threadIdx.x;
    if (t < 48) cb[t] = (t < 16) ? qcb[t] : (t < 32 ? kcb[t - 16] : vcb[t - 32]);
    __syncthreads();
    size_t idx = ((size_t)blockIdx.x * 256 + t) * 8;   // elem index into W
    int o = (int)(idx >> 12);        // D == 4096 == 2^12
    int c = (int)(idx & 4095);
    const int* codes; const float* scales; int cbo; int ro;
    if (o < QO)           { codes = qc; scales = qs; cbo = 0;  ro = o; }
    else if (o < QO + KO) { codes = kc; scales = ks; cbo = 16; ro = o - QO; }
    else                  { codes = vc; scales = vs; cbo = 32; ro = o - QO - KO; }
    float s = scales[ro * (D / 128) + (c >> 7)];       // GROUP = 128
    const int4* cp = (const int4*)(codes + (size_t)ro * D + c);
    int4 c0 = cp[0], c1 = cp[1];
    union { bf16 h[8]; uint4 u; } pk;
    pk.h[0] = __float2bfloat16(cb[cbo + c0.x] * s);
    pk.h[1] = __float2bfloat16(cb[cbo + c0.y] * s);
    pk.h[2] = __float2bfloat16(cb[cbo + c0.z] * s);
    pk.h[3] = __float2bfloat16(cb[cbo + c0.w] * s);
    pk.h[4] = __float2bfloat16(cb[cbo + c1.x] * s);
    pk.h[5] = __float2bfloat16(cb[cbo + c1.y] * s);
    pk.h[6] = __float2bfloat16(cb[cbo + c1.z] * s);
    pk.h[7] = __float2bfloat16(cb[cbo + c1.w] * s);
    *(uint4*)(W + idx) = pk.u;
}

// ---------------- bf16 MFMA GEMM: C[T,NO] = X[T,D] * W[NO,D]^T ----------------
// 128x128 tile, BK=64, 256 threads = 4 waves in 2x2, each wave 64x64 (4x4 MFMA tiles)
//
// LDS bank-conflict fix (R1): row stride is 128 B == one full bank rotation, so the
// un-swizzled fragment read (16 lanes, 16 rows, same col) was a 16-way conflict
// (SQ_LDS_BANK_CONFLICT 1.51e8 ~= 37% of kernel cycles). XOR-swizzle the 16 B chunk
// slot within each row: slot = chunk ^ (row & 7). global_load_lds writes lane L at
// base + L*16 (fixed), so the swizzle is applied by permuting each lane's GLOBAL
// source chunk (same cache lines, coalescing preserved). Read side: 16 lanes then
// spread across all 32 banks, 2 lanes/bank = free (m136).
#define BM 128
#define BN 128
#define BK 64

#define ASYNC16(g, l)                                              \
    __builtin_amdgcn_global_load_lds(                              \
        (const __attribute__((address_space(1))) void*)(g),        \
        (__attribute__((address_space(3))) void*)(l), 16, 0, 0)

__global__ __launch_bounds__(256) void gemm_qkv_kernel(
    const bf16* __restrict__ A,   // [Tn][D] bf16
    const bf16* __restrict__ Bm,  // [NO][D] bf16
    float* __restrict__ out) {
    __shared__ __align__(16) bf16 lA[BM * BK];  // 16 KB, row stride BK (128 B)
    __shared__ __align__(16) bf16 lB[BN * BK];  // 16 KB

    const int t    = threadIdx.x;
    const int wave = t >> 6;
    const int lane = t & 63;

    const int m0 = blockIdx.y * BM;
    const int n0 = blockIdx.x * BN;

    const int wm = (wave >> 1) * 64;   // wave row offset in tile
    const int wn = (wave & 1) * 64;    // wave col offset in tile

    f32x4 acc[4][4] = {};

    // staging: per wave-issue, 64 lanes x 16B = 8 rows of BK=64 bf16
    const int srow   = lane >> 3;               // 0..7 row within issue
    const int spos   = lane & 7;                // LDS chunk slot (fixed by HW)
    const int gchunk = spos ^ srow;             // swizzled global source chunk
    const int scol   = gchunk * 8;              // global col offset (bf16 elems)

    const int quad  = lane >> 4;         // 0..3
    const int l16   = lane & 15;
    const int xkey  = l16 & 7;           // row & 7 for fragment rows (rows are 8-aligned)

    for (int kt = 0; kt < D; kt += BK) {
        #pragma unroll
        for (int i = 0; i < 4; ++i) {
            int row = (wave * 4 + i) * 8 + srow;                  // 0..127
            const bf16* gA = A + (size_t)(m0 + row) * D + kt + scol;
            ASYNC16(gA, &lA[(wave * 4 + i) * 8 * BK]);
            const bf16* gB = Bm + (size_t)(n0 + row) * D + kt + scol;
            ASYNC16(gB, &lB[(wave * 4 + i) * 8 * BK]);
        }
        __syncthreads();   // vmcnt(0) drain before s_barrier

        #pragma unroll
        for (int s = 0; s < 2; ++s) {
            bf16x8 af[4], bfr[4];
            const int cc   = s * 4 + quad;        // 16B chunk index within row
            const int slot = (cc ^ xkey) * 8;     // swizzled chunk -> elem offset
            #pragma unroll
            for (int i = 0; i < 4; ++i)
                af[i] = *(const bf16x8*)&lA[(wm + i * 16 + l16) * BK + slot];
            #pragma unroll
            for (int j = 0; j < 4; ++j)
                bfr[j] = *(const bf16x8*)&lB[(wn + j * 16 + l16) * BK + slot];
            #pragma unroll
            for (int i = 0; i < 4; ++i)
                #pragma unroll
                for (int j = 0; j < 4; ++j)
                    acc[i][j] = __builtin_amdgcn_mfma_f32_16x16x32_bf16(
                        af[i], bfr[j], acc[i][j], 0, 0, 0);
        }
        __syncthreads();
    }

    // epilogue: map fused column block -> q/k/v output region
    float* base; int ld, c0;
    if (n0 < QO)           { base = out;                               ld = QO; c0 = n0; }
    else if (n0 < QO + KO) { base = out + (size_t)Tn * QO;             ld = KO; c0 = n0 - QO; }
    else                   { base = out + (size_t)Tn * QO + (size_t)Tn * KO; ld = VO; c0 = n0 - QO - KO; }

    const int rquad = quad * 4;   // C/D layout: col = lane&15, row = quad*4 + reg
    #pragma unroll
    for (int i = 0; i < 4; ++i) {
        #pragma unroll
        for (int j = 0; j < 4; ++j) {
            int gc = c0 + wn + j * 16 + l16;
            #pragma unroll
            for (int r = 0; r < 4; ++r) {
                int gr = m0 + wm + i * 16 + rquad + r;
                base[(size_t)gr * ld + gc] = acc[i][j][r];
            }
        }
    }
}

extern "C" void kernel_launch(void* const* d_in, const int* in_sizes, int n_in,
                              void* d_out, int out_size, void* d_ws, size_t ws_size,
                              hipStream_t stream) {
    const float* x   = (const float*)d_in[0];
    const int*   qc  = (const int*)  d_in[1];
    const float* qs  = (const float*)d_in[2];
    const float* qcb = (const float*)d_in[3];
    const int*   kc  = (const int*)  d_in[4];
    const float* ks  = (const float*)d_in[5];
    const float* kcb = (const float*)d_in[6];
    const int*   vc  = (const int*)  d_in[7];
    const float* vs  = (const float*)d_in[8];
    const float* vcb = (const float*)d_in[9];
    float* out = (float*)d_out;

    // workspace: xb = 64 MB, W = 48 MB (112 MB total)
    bf16* xb = (bf16*)d_ws;
    bf16* W  = (bf16*)((char*)d_ws + (size_t)Tn * D * sizeof(bf16));

    cast_x_kernel<<<(Tn * D) / (8 * 256), 256, 0, stream>>>(x, xb);
    dequant_kernel<<<((size_t)NO * D) / (8 * 256), 256, 0, stream>>>(
        qc, qs, qcb, kc, ks, kcb, vc, vs, vcb, W);
    dim3 grid(NO / BN, Tn / BM);
    gemm_qkv_kernel<<<grid, 256, 0, stream>>>(xb, W, out);
}

// Round 3
// 887.489 us; speedup vs baseline: 1.0831x; 1.0268x over previous
//
#include <hip/hip_runtime.h>
#include <hip/hip_bf16.h>

using bf16 = __hip_bfloat16;
typedef __attribute__((ext_vector_type(16))) float f32x16;
typedef __attribute__((ext_vector_type(8))) __bf16 bf16x8;

static constexpr int Tn = 8192;           // tokens = B*S = 4*2048
static constexpr int D  = 4096;           // in features (K)
static constexpr int QO = 4096, KO = 1024, VO = 1024;
static constexpr int NO = QO + KO + VO;   // 6144 fused out features

// ---------------- cast x fp32 -> bf16 (8 elems/thread) ----------------
__global__ void cast_x_kernel(const float* __restrict__ x, bf16* __restrict__ xb) {
    size_t i = ((size_t)blockIdx.x * blockDim.x + threadIdx.x) * 8;
    float4 a = *(const float4*)(x + i);
    float4 b = *(const float4*)(x + i + 4);
    union { bf16 h[8]; uint4 u; } pk;
    pk.h[0] = __float2bfloat16(a.x); pk.h[1] = __float2bfloat16(a.y);
    pk.h[2] = __float2bfloat16(a.z); pk.h[3] = __float2bfloat16(a.w);
    pk.h[4] = __float2bfloat16(b.x); pk.h[5] = __float2bfloat16(b.y);
    pk.h[6] = __float2bfloat16(b.z); pk.h[7] = __float2bfloat16(b.w);
    *(uint4*)(xb + i) = pk.u;
}

// ------------- dequant q/k/v codes -> fused bf16 W [NO][D] -------------
__global__ void dequant_kernel(
    const int* __restrict__ qc, const float* __restrict__ qs, const float* __restrict__ qcb,
    const int* __restrict__ kc, const float* __restrict__ ks, const float* __restrict__ kcb,
    const int* __restrict__ vc, const float* __restrict__ vs, const float* __restrict__ vcb,
    bf16* __restrict__ W) {
    __shared__ float cb[48];
    int t = threadIdx.x;
    if (t < 48) cb[t] = (t < 16) ? qcb[t] : (t < 32 ? kcb[t - 16] : vcb[t - 32]);
    __syncthreads();
    size_t idx = ((size_t)blockIdx.x * 256 + t) * 8;   // elem index into W
    int o = (int)(idx >> 12);        // D == 4096 == 2^12
    int c = (int)(idx & 4095);
    const int* codes; const float* scales; int cbo; int ro;
    if (o < QO)           { codes = qc; scales = qs; cbo = 0;  ro = o; }
    else if (o < QO + KO) { codes = kc; scales = ks; cbo = 16; ro = o - QO; }
    else                  { codes = vc; scales = vs; cbo = 32; ro = o - QO - KO; }
    float s = scales[ro * (D / 128) + (c >> 7)];       // GROUP = 128
    const int4* cp = (const int4*)(codes + (size_t)ro * D + c);
    int4 c0 = cp[0], c1 = cp[1];
    union { bf16 h[8]; uint4 u; } pk;
    pk.h[0] = __float2bfloat16(cb[cbo + c0.x] * s);
    pk.h[1] = __float2bfloat16(cb[cbo + c0.y] * s);
    pk.h[2] = __float2bfloat16(cb[cbo + c0.z] * s);
    pk.h[3] = __float2bfloat16(cb[cbo + c0.w] * s);
    pk.h[4] = __float2bfloat16(cb[cbo + c1.x] * s);
    pk.h[5] = __float2bfloat16(cb[cbo + c1.y] * s);
    pk.h[6] = __float2bfloat16(cb[cbo + c1.z] * s);
    pk.h[7] = __float2bfloat16(cb[cbo + c1.w] * s);
    *(uint4*)(W + idx) = pk.u;
}

// ---------------- bf16 MFMA GEMM: C[T,NO] = X[T,D] * W[NO,D]^T ----------------
// 128x128 tile, BK=64, 256 threads = 4 waves (2x2), wave tile 64x64.
// R2 changes:
//  * 32x32x16 MFMA (half the instructions, ~15% better pipe rate per m119);
//    wave tile = 2x2 grid of 32x32, acc = 4 x f32x16 (64 regs, unchanged).
//  * Double-buffered LDS, ONE barrier per K-iter; async loads for the next
//    tile are issued right after the barrier into the opposite buffer, so the
//    vmcnt(0) drain at the next barrier has a full compute phase of slack.
//  * XOR swizzle retained (R1): LDS slot s of row r holds global chunk s^(r&7);
//    read slot = cc ^ (row&7). Verified conflict-free (SQ_LDS_BANK_CONFLICT=0).
#define BM 128
#define BN 128
#define BK 64

#define ASYNC16(g, l)                                              \
    __builtin_amdgcn_global_load_lds(                              \
        (const __attribute__((address_space(1))) void*)(g),        \
        (__attribute__((address_space(3))) void*)(l), 16, 0, 0)

__global__ __launch_bounds__(256) void gemm_qkv_kernel(
    const bf16* __restrict__ A,   // [Tn][D] bf16
    const bf16* __restrict__ Bm,  // [NO][D] bf16
    float* __restrict__ out) {
    __shared__ __align__(16) bf16 lA[2][BM * BK];  // 2 x 16 KB
    __shared__ __align__(16) bf16 lB[2][BN * BK];  // 2 x 16 KB

    const int t    = threadIdx.x;
    const int wave = t >> 6;
    const int lane = t & 63;

    const int m0 = blockIdx.y * BM;
    const int n0 = blockIdx.x * BN;

    const int wm = (wave >> 1) * 64;   // wave row offset in tile
    const int wn = (wave & 1) * 64;    // wave col offset in tile

    f32x16 acc[2][2] = {};

    // staging: per wave-issue, 64 lanes x 16B = 8 rows of BK=64 bf16
    const int srow   = lane >> 3;               // 0..7 row within issue
    const int spos   = lane & 7;                // LDS chunk slot (fixed by HW)
    const int scol   = (spos ^ srow) * 8;       // swizzled global source chunk

    const int l32   = lane & 31;
    const int khalf = lane >> 5;         // k-half: lanes 0-31 k=0..7, 32-63 k=8..15
    const int xkey  = lane & 7;          // row & 7 for fragment rows

    for (int kt = 0; kt < D; kt += BK) {
        const int cur = (kt >> 6) & 1;
        if (kt == 0) {
            // prologue stage into buf 0
            #pragma unroll
            for (int i = 0; i < 4; ++i) {
                int row = (wave * 4 + i) * 8 + srow;
                ASYNC16(A  + (size_t)(m0 + row) * D + scol, &lA[0][(wave * 4 + i) * 8 * BK]);
                ASYNC16(Bm + (size_t)(n0 + row) * D + scol, &lB[0][(wave * 4 + i) * 8 * BK]);
            }
        }
        __syncthreads();   // drains vmcnt(0): buf[cur] is ready; buf[cur^1] readers done
        if (kt + BK < D) {
            const int nb = cur ^ 1;
            #pragma unroll
            for (int i = 0; i < 4; ++i) {
                int row = (wave * 4 + i) * 8 + srow;
                ASYNC16(A  + (size_t)(m0 + row) * D + kt + BK + scol, &lA[nb][(wave * 4 + i) * 8 * BK]);
                ASYNC16(Bm + (size_t)(n0 + row) * D + kt + BK + scol, &lB[nb][(wave * 4 + i) * 8 * BK]);
            }
        }
        #pragma unroll
        for (int ks = 0; ks < 4; ++ks) {
            const int cc   = ks * 2 + khalf;      // 16B chunk index within row
            const int slot = (cc ^ xkey) * 8;     // swizzled chunk -> elem offset
            bf16x8 af0 = *(const bf16x8*)&lA[cur][(wm      + l32) * BK + slot];
            bf16x8 af1 = *(const bf16x8*)&lA[cur][(wm + 32 + l32) * BK + slot];
            bf16x8 bf0 = *(const bf16x8*)&lB[cur][(wn      + l32) * BK + slot];
            bf16x8 bf1 = *(const bf16x8*)&lB[cur][(wn + 32 + l32) * BK + slot];
            acc[0][0] = __builtin_amdgcn_mfma_f32_32x32x16_bf16(af0, bf0, acc[0][0], 0, 0, 0);
            acc[0][1] = __builtin_amdgcn_mfma_f32_32x32x16_bf16(af0, bf1, acc[0][1], 0, 0, 0);
            acc[1][0] = __builtin_amdgcn_mfma_f32_32x32x16_bf16(af1, bf0, acc[1][0], 0, 0, 0);
            acc[1][1] = __builtin_amdgcn_mfma_f32_32x32x16_bf16(af1, bf1, acc[1][1], 0, 0, 0);
        }
    }

    // epilogue: map fused column block -> q/k/v output region
    float* base; int ld, c0;
    if (n0 < QO)           { base = out;                               ld = QO; c0 = n0; }
    else if (n0 < QO + KO) { base = out + (size_t)Tn * QO;             ld = KO; c0 = n0 - QO; }
    else                   { base = out + (size_t)Tn * QO + (size_t)Tn * KO; ld = VO; c0 = n0 - QO - KO; }

    // 32x32 C/D layout (m74/m101): col = lane&31, row = (reg&3) + 8*(reg>>2) + 4*(lane>>5)
    const int rbase = 4 * khalf;
    #pragma unroll
    for (int mt = 0; mt < 2; ++mt) {
        #pragma unroll
        for (int nt = 0; nt < 2; ++nt) {
            int gc = c0 + wn + nt * 32 + l32;
            #pragma unroll
            for (int reg = 0; reg < 16; ++reg) {
                int gr = m0 + wm + mt * 32 + (reg & 3) + 8 * (reg >> 2) + rbase;
                base[(size_t)gr * ld + gc] = acc[mt][nt][reg];
            }
        }
    }
}

extern "C" void kernel_launch(void* const* d_in, const int* in_sizes, int n_in,
                              void* d_out, int out_size, void* d_ws, size_t ws_size,
                              hipStream_t stream) {
    const float* x   = (const float*)d_in[0];
    const int*   qc  = (const int*)  d_in[1];
    const float* qs  = (const float*)d_in[2];
    const float* qcb = (const float*)d_in[3];
    const int*   kc  = (const int*)  d_in[4];
    const float* ks  = (const float*)d_in[5];
    const float* kcb = (const float*)d_in[6];
    const int*   vc  = (const int*)  d_in[7];
    const float* vs  = (const float*)d_in[8];
    const float* vcb = (const float*)d_in[9];
    float* out = (float*)d_out;

    // workspace: xb = 64 MB, W = 48 MB (112 MB total)
    bf16* xb = (bf16*)d_ws;
    bf16* W  = (bf16*)((char*)d_ws + (size_t)Tn * D * sizeof(bf16));

    cast_x_kernel<<<(Tn * D) / (8 * 256), 256, 0, stream>>>(x, xb);
    dequant_kernel<<<((size_t)NO * D) / (8 * 256), 256, 0, stream>>>(
        qc, qs, qcb, kc, ks, kcb, vc, vs, vcb, W);
    dim3 grid(NO / BN, Tn / BM);
    gemm_qkv_kernel<<<grid, 256, 0, stream>>>(xb, W, out);
}